// Round 10
// baseline (679.460 us; speedup 1.0000x reference)
//
#include <hip/hip_runtime.h>
#include <hip/hip_bf16.h>
#include <math.h>

#define TT 512
#define NN 200
#define HH 64
#define EE 16
#define RR 10
#define MU_OFF 0
#define COV_OFF (TT*NN)      // 102400
#define HBLK (NN*NN)         // 40000 floats per t-block of cov
#define HPAD 68              // padded hist row

__device__ __forceinline__ float sigmoidf_(float x) {
    return 1.0f / (1.0f + __expf(-x));
}
__device__ __forceinline__ float tanhf_(float x) {
    x = fminf(15.0f, fmaxf(-15.0f, x));
    float e = __expf(2.0f * x);
    return (e - 1.0f) / (e + 1.0f);
}
// unified gate activation: sigmoid(g) or tanh(g)=2*sigmoid(2g)-1
__device__ __forceinline__ float act_(float g, bool is_tanh) {
    float xx = is_tanh ? 2.0f * g : g;
    float e = __expf(-xx);
    float v = 1.0f / (1.0f + e);
    return is_tanh ? fmaf(2.0f, v, -1.0f) : v;
}

// quad_perm DPP xor-swaps (VALU pipe, not LDS pipe)
__device__ __forceinline__ float dppxor1(float v) {   // lanes [1,0,3,2]
    return __int_as_float(__builtin_amdgcn_mov_dpp(__float_as_int(v), 0xB1, 0xf, 0xf, true));
}
__device__ __forceinline__ float dppxor2(float v) {   // lanes [2,3,0,1]
    return __int_as_float(__builtin_amdgcn_mov_dpp(__float_as_int(v), 0x4E, 0xf, 0xf, true));
}

// Raw wave-counted barrier: waits LDS only (lgkmcnt), never drains vmcnt,
// so the periodic global flush stores float across ticks.
#define BAR() do { asm volatile("s_waitcnt lgkmcnt(0)" ::: "memory"); \
                   __builtin_amdgcn_s_barrier();                      \
                   asm volatile("" ::: "memory"); } while (0)

#define PIN4(v) asm volatile("" : "+v"(v.x), "+v"(v.y), "+v"(v.z), "+v"(v.w))
#define RM4(M) M(0) M(1) M(2) M(3)

// ---------------- Kernel A: 2-layer LSTM, 2 batch elements per WG ----------
// R7 chassis (quad-split, 2 barriers/tick) but each WG advances TWO
// independent batch elements (n, n+100) with the SAME weight registers:
// per-tick issue ~doubles but fills the ~750cy latency slack (ds_read,
// trans, barriers) that 2 waves/SIMD could not hide -> ~2x throughput.
//   tid<256 : layer0 of both elements (Whh0 rows in regs, 64 floats)
//   tid>=256: layer1 of both elements (Wih1+Whh1 rows, 128 floats)
// Update: lanes 0-63 element a, 64-127 element b (per layer).
__global__
__attribute__((amdgpu_flat_work_group_size(512, 512), amdgpu_waves_per_eu(2, 2)))
void lstm_kernel(
    const float* __restrict__ inputs,
    const float* __restrict__ Wih0, const float* __restrict__ Whh0,
    const float* __restrict__ bih0, const float* __restrict__ bhh0,
    const float* __restrict__ Wih1, const float* __restrict__ Whh1,
    const float* __restrict__ bih1, const float* __restrict__ bhh1,
    float* __restrict__ out)
{
    const int na  = blockIdx.x;          // element a
    const int nb  = blockIdx.x + 100;    // element b
    const int tid = threadIdx.x;

    __shared__ float xsa[TT], xsb[TT];
    __shared__ float h0sa[HH], h0sb[HH], h1sa[HH], h1sb[HH];
    __shared__ float ga0a[256], ga0b[256];   // activated layer0 gates
    __shared__ float ga1a[256], ga1b[256];   // activated layer1 gates
    __shared__ float hista[64][HPAD];        // h1 history, element a
    __shared__ float histb[64][HPAD];        // h1 history, element b

    xsa[tid] = inputs[tid * NN + na];
    xsb[tid] = inputs[tid * NN + nb];
    if (tid < HH) {
        h0sa[tid] = 0.0f; h0sb[tid] = 0.0f;
        h1sa[tid] = 0.0f; h1sb[tid] = 0.0f;
    }

    float* covA = out + COV_OFF + na * HH;
    float* covB = out + COV_OFF + nb * HH;

    if (tid < 256) {
        // ================= layer-0 branch (waves 0-3) =================
        const int b4 = tid & ~3;        // first of this thread's 4 rows
        const int qr = tid & 3;         // k-quarter (16 floats)
#define DECLA(m) \
        float4 wA##m##_0, wA##m##_1, wA##m##_2, wA##m##_3; \
        { const float4* p = (const float4*)(Whh0 + (b4 + m) * HH + qr * 16); \
          wA##m##_0 = p[0]; wA##m##_1 = p[1]; wA##m##_2 = p[2]; wA##m##_3 = p[3]; \
          PIN4(wA##m##_0); PIN4(wA##m##_1); PIN4(wA##m##_2); PIN4(wA##m##_3); }
        RM4(DECLA)
#define DECLAC(m) const float wx##m = Wih0[b4 + m]; \
                  const float bb##m = bih0[b4 + m] + bhh0[b4 + m];
        RM4(DECLAC)
        const bool is_t = ((tid >> 6) == 2);   // gate-2 rows use tanh
        float c0 = 0.0f;   // lanes 0-63: c0 of element a; 64-127: element b

        BAR();  // init

        for (int t = 0; t <= TT; ++t) {
            if (t < TT) {
#define MVA(m) { \
                float a = (qr == 0) ? fmaf(wx##m, x, bb##m) : 0.0f; \
                a = fmaf(wA##m##_0.x, hc0.x, a); \
                a = fmaf(wA##m##_0.y, hc0.y, a); \
                a = fmaf(wA##m##_0.z, hc0.z, a); \
                a = fmaf(wA##m##_0.w, hc0.w, a); \
                a = fmaf(wA##m##_1.x, hc1.x, a); \
                a = fmaf(wA##m##_1.y, hc1.y, a); \
                a = fmaf(wA##m##_1.z, hc1.z, a); \
                a = fmaf(wA##m##_1.w, hc1.w, a); \
                a = fmaf(wA##m##_2.x, hc2.x, a); \
                a = fmaf(wA##m##_2.y, hc2.y, a); \
                a = fmaf(wA##m##_2.z, hc2.z, a); \
                a = fmaf(wA##m##_2.w, hc2.w, a); \
                a = fmaf(wA##m##_3.x, hc3.x, a); \
                a = fmaf(wA##m##_3.y, hc3.y, a); \
                a = fmaf(wA##m##_3.z, hc3.z, a); \
                a = fmaf(wA##m##_3.w, hc3.w, a); \
                acc##m = a; }
                {   // ---- element a ----
                    const float x = xsa[t];
                    const float4* hq = (const float4*)(h0sa + qr * 16);
                    float4 hc0 = hq[0], hc1 = hq[1], hc2 = hq[2], hc3 = hq[3];
                    float acc0, acc1, acc2, acc3;
                    RM4(MVA)
                    acc0 += dppxor1(acc0); acc0 += dppxor2(acc0);
                    acc1 += dppxor1(acc1); acc1 += dppxor2(acc1);
                    acc2 += dppxor1(acc2); acc2 += dppxor2(acc2);
                    acc3 += dppxor1(acc3); acc3 += dppxor2(acc3);
                    float g = (qr == 0) ? acc0 : (qr == 1) ? acc1 : (qr == 2) ? acc2 : acc3;
                    ga0a[tid] = act_(g, is_t);
                }
                {   // ---- element b ----
                    const float x = xsb[t];
                    const float4* hq = (const float4*)(h0sb + qr * 16);
                    float4 hc0 = hq[0], hc1 = hq[1], hc2 = hq[2], hc3 = hq[3];
                    float acc0, acc1, acc2, acc3;
                    RM4(MVA)
                    acc0 += dppxor1(acc0); acc0 += dppxor2(acc0);
                    acc1 += dppxor1(acc1); acc1 += dppxor2(acc1);
                    acc2 += dppxor1(acc2); acc2 += dppxor2(acc2);
                    acc3 += dppxor1(acc3); acc3 += dppxor2(acc3);
                    float g = (qr == 0) ? acc0 : (qr == 1) ? acc1 : (qr == 2) ? acc2 : acc3;
                    ga0b[tid] = act_(g, is_t);
                }
            }
            BAR();
            if (t < TT) {
                if (tid < 64) {
                    float ia = ga0a[tid], fa = ga0a[tid + 64];
                    float gg = ga0a[tid + 128], oa = ga0a[tid + 192];
                    c0 = fmaf(fa, c0, ia * gg);
                    h0sa[tid] = oa * tanhf_(c0);
                } else if (tid < 128) {
                    const int j = tid - 64;
                    float ia = ga0b[j], fa = ga0b[j + 64];
                    float gg = ga0b[j + 128], oa = ga0b[j + 192];
                    c0 = fmaf(fa, c0, ia * gg);
                    h0sb[j] = oa * tanhf_(c0);
                }
            }
            BAR();
            if ((t & 63) == 0 && t > 0) {   // flush element a: steps t-64..t-1
                const int s = tid >> 2;          // row 0..63
                const int c = (tid & 3) * 16;    // 16 floats per thread
                float4 v0 = *(const float4*)&hista[s][c];
                float4 v1 = *(const float4*)&hista[s][c + 4];
                float4 v2 = *(const float4*)&hista[s][c + 8];
                float4 v3 = *(const float4*)&hista[s][c + 12];
                float* dst = covA + (size_t)(t - 64 + s) * HBLK + c;
                ((float4*)dst)[0] = v0; ((float4*)dst)[1] = v1;
                ((float4*)dst)[2] = v2; ((float4*)dst)[3] = v3;
            }
        }
    } else {
        // ================= layer-1 branch (waves 4-7), step t-1 ========
        const int r  = tid - 256;
        const int b4 = r & ~3;
        const int qr = r & 3;
#define DECLB(m) \
        float4 wI##m##_0, wI##m##_1, wI##m##_2, wI##m##_3; \
        float4 wH##m##_0, wH##m##_1, wH##m##_2, wH##m##_3; \
        { const float4* p = (const float4*)(Wih1 + (b4 + m) * HH + qr * 16); \
          wI##m##_0 = p[0]; wI##m##_1 = p[1]; wI##m##_2 = p[2]; wI##m##_3 = p[3]; \
          PIN4(wI##m##_0); PIN4(wI##m##_1); PIN4(wI##m##_2); PIN4(wI##m##_3); \
          const float4* q2 = (const float4*)(Whh1 + (b4 + m) * HH + qr * 16); \
          wH##m##_0 = q2[0]; wH##m##_1 = q2[1]; wH##m##_2 = q2[2]; wH##m##_3 = q2[3]; \
          PIN4(wH##m##_0); PIN4(wH##m##_1); PIN4(wH##m##_2); PIN4(wH##m##_3); }
        RM4(DECLB)
#define DECLBC(m) const float bB##m = bih1[b4 + m] + bhh1[b4 + m];
        RM4(DECLBC)
        const bool is_t = ((r >> 6) == 2);
        float c1 = 0.0f;   // lanes r 0-63: element a; 64-127: element b

        BAR();  // init

        for (int t = 0; t <= TT; ++t) {
            if (t >= 1) {
#define MVB(m) { \
                float a = (qr == 0) ? bB##m : 0.0f; \
                float s2 = 0.0f; \
                a  = fmaf(wI##m##_0.x, xc0.x, a); \
                a  = fmaf(wI##m##_0.y, xc0.y, a); \
                a  = fmaf(wI##m##_0.z, xc0.z, a); \
                a  = fmaf(wI##m##_0.w, xc0.w, a); \
                a  = fmaf(wI##m##_1.x, xc1.x, a); \
                a  = fmaf(wI##m##_1.y, xc1.y, a); \
                a  = fmaf(wI##m##_1.z, xc1.z, a); \
                a  = fmaf(wI##m##_1.w, xc1.w, a); \
                a  = fmaf(wI##m##_2.x, xc2.x, a); \
                a  = fmaf(wI##m##_2.y, xc2.y, a); \
                a  = fmaf(wI##m##_2.z, xc2.z, a); \
                a  = fmaf(wI##m##_2.w, xc2.w, a); \
                a  = fmaf(wI##m##_3.x, xc3.x, a); \
                a  = fmaf(wI##m##_3.y, xc3.y, a); \
                a  = fmaf(wI##m##_3.z, xc3.z, a); \
                a  = fmaf(wI##m##_3.w, xc3.w, a); \
                s2 = fmaf(wH##m##_0.x, yc0.x, s2); \
                s2 = fmaf(wH##m##_0.y, yc0.y, s2); \
                s2 = fmaf(wH##m##_0.z, yc0.z, s2); \
                s2 = fmaf(wH##m##_0.w, yc0.w, s2); \
                s2 = fmaf(wH##m##_1.x, yc1.x, s2); \
                s2 = fmaf(wH##m##_1.y, yc1.y, s2); \
                s2 = fmaf(wH##m##_1.z, yc1.z, s2); \
                s2 = fmaf(wH##m##_1.w, yc1.w, s2); \
                s2 = fmaf(wH##m##_2.x, yc2.x, s2); \
                s2 = fmaf(wH##m##_2.y, yc2.y, s2); \
                s2 = fmaf(wH##m##_2.z, yc2.z, s2); \
                s2 = fmaf(wH##m##_2.w, yc2.w, s2); \
                s2 = fmaf(wH##m##_3.x, yc3.x, s2); \
                s2 = fmaf(wH##m##_3.y, yc3.y, s2); \
                s2 = fmaf(wH##m##_3.z, yc3.z, s2); \
                s2 = fmaf(wH##m##_3.w, yc3.w, s2); \
                acc##m = a + s2; }
                {   // ---- element a ----
                    const float4* xq = (const float4*)(h0sa + qr * 16);
                    const float4* yq = (const float4*)(h1sa + qr * 16);
                    float4 xc0 = xq[0], xc1 = xq[1], xc2 = xq[2], xc3 = xq[3];
                    float4 yc0 = yq[0], yc1 = yq[1], yc2 = yq[2], yc3 = yq[3];
                    float acc0, acc1, acc2, acc3;
                    RM4(MVB)
                    acc0 += dppxor1(acc0); acc0 += dppxor2(acc0);
                    acc1 += dppxor1(acc1); acc1 += dppxor2(acc1);
                    acc2 += dppxor1(acc2); acc2 += dppxor2(acc2);
                    acc3 += dppxor1(acc3); acc3 += dppxor2(acc3);
                    float g = (qr == 0) ? acc0 : (qr == 1) ? acc1 : (qr == 2) ? acc2 : acc3;
                    ga1a[r] = act_(g, is_t);
                }
                {   // ---- element b ----
                    const float4* xq = (const float4*)(h0sb + qr * 16);
                    const float4* yq = (const float4*)(h1sb + qr * 16);
                    float4 xc0 = xq[0], xc1 = xq[1], xc2 = xq[2], xc3 = xq[3];
                    float4 yc0 = yq[0], yc1 = yq[1], yc2 = yq[2], yc3 = yq[3];
                    float acc0, acc1, acc2, acc3;
                    RM4(MVB)
                    acc0 += dppxor1(acc0); acc0 += dppxor2(acc0);
                    acc1 += dppxor1(acc1); acc1 += dppxor2(acc1);
                    acc2 += dppxor1(acc2); acc2 += dppxor2(acc2);
                    acc3 += dppxor1(acc3); acc3 += dppxor2(acc3);
                    float g = (qr == 0) ? acc0 : (qr == 1) ? acc1 : (qr == 2) ? acc2 : acc3;
                    ga1b[r] = act_(g, is_t);
                }
            }
            BAR();
            if (t >= 1) {
                if (r < 64) {
                    float ia = ga1a[r], fa = ga1a[r + 64];
                    float gg = ga1a[r + 128], oa = ga1a[r + 192];
                    c1 = fmaf(fa, c1, ia * gg);
                    float h1 = oa * tanhf_(c1);
                    h1sa[r] = h1;
                    hista[(t - 1) & 63][r] = h1;
                } else if (r < 128) {
                    const int j = r - 64;
                    float ia = ga1b[j], fa = ga1b[j + 64];
                    float gg = ga1b[j + 128], oa = ga1b[j + 192];
                    c1 = fmaf(fa, c1, ia * gg);
                    float h1 = oa * tanhf_(c1);
                    h1sb[j] = h1;
                    histb[(t - 1) & 63][j] = h1;
                }
            }
            BAR();
            if ((t & 63) == 0 && t > 0) {   // flush element b: steps t-64..t-1
                const int s = r >> 2;            // row 0..63
                const int c = (r & 3) * 16;      // 16 floats per thread
                float4 v0 = *(const float4*)&histb[s][c];
                float4 v1 = *(const float4*)&histb[s][c + 4];
                float4 v2 = *(const float4*)&histb[s][c + 8];
                float4 v3 = *(const float4*)&histb[s][c + 12];
                float* dst = covB + (size_t)(t - 64 + s) * HBLK + c;
                ((float4*)dst)[0] = v0; ((float4*)dst)[1] = v1;
                ((float4*)dst)[2] = v2; ((float4*)dst)[3] = v3;
            }
        }
    }
}

// ---------------- Kernel B: heads + covariance, one workgroup per t ----------
__global__ __launch_bounds__(256) void head_kernel(
    const float* __restrict__ embW, const int* __restrict__ indices,
    const float* __restrict__ Wm, const float* __restrict__ bm,
    const float* __restrict__ Wv, const float* __restrict__ bv,
    const float* __restrict__ Wd, const float* __restrict__ bd,
    float* __restrict__ out)
{
    const int t = blockIdx.x;
    const int tid = threadIdx.x;

    __shared__ float hs[NN * HH];          // 12800
    __shared__ float embs[NN * EE];        // 3200
    __shared__ float Wvs[(HH + EE) * RR];  // 800
    __shared__ float Wms[HH + EE];
    __shared__ float Wds[HH + EE];
    __shared__ float Vs[NN * (RR + 1)];    // stride 11 to dodge bank conflicts
    __shared__ float dsh[NN];
    __shared__ float bvs[RR];

    const float* hsrc = out + COV_OFF + (size_t)t * HBLK;
    for (int i = tid; i < (NN * HH) / 4; i += 256)
        ((float4*)hs)[i] = ((const float4*)hsrc)[i];
    for (int i = tid; i < NN * EE; i += 256) {
        int n = i >> 4, e = i & 15;
        embs[i] = embW[indices[n] * EE + e];
    }
    for (int i = tid; i < (HH + EE) * RR; i += 256) Wvs[i] = Wv[i];
    if (tid < HH + EE) { Wms[tid] = Wm[tid]; Wds[tid] = Wd[tid]; }
    if (tid < RR) bvs[tid] = bv[tid];
    __syncthreads();

    // V = y @ Wv + bv
    for (int p = tid; p < NN * RR; p += 256) {
        int n = p / RR, r = p - n * RR;
        const float* hn = hs + n * HH;
        const float* en = embs + n * EE;
        float acc = bvs[r];
#pragma unroll 8
        for (int k = 0; k < HH; ++k) acc = fmaf(hn[k], Wvs[k * RR + r], acc);
#pragma unroll
        for (int k = 0; k < EE; ++k) acc = fmaf(en[k], Wvs[(HH + k) * RR + r], acc);
        Vs[n * (RR + 1) + r] = acc;
    }
    // mu and d
    const float bmv = bm[0], bdv = bd[0];
    for (int n = tid; n < NN; n += 256) {
        const float* hn = hs + n * HH;
        const float* en = embs + n * EE;
        float am = bmv, ad = bdv;
#pragma unroll 8
        for (int k = 0; k < HH; ++k) {
            float h = hn[k];
            am = fmaf(h, Wms[k], am);
            ad = fmaf(h, Wds[k], ad);
        }
#pragma unroll
        for (int k = 0; k < EE; ++k) {
            float e = en[k];
            am = fmaf(e, Wms[HH + k], am);
            ad = fmaf(e, Wds[HH + k], ad);
        }
        out[MU_OFF + t * NN + n] = am;
        dsh[n] = (ad > 20.0f) ? ad : log1pf(__expf(ad));  // softplus
    }
    __syncthreads();

    // cov[t] = V V^T + diag(d)  — overwrites the whole block (incl. stashed h)
    float* covp = out + COV_OFF + (size_t)t * HBLK;
    for (int p = tid; p < NN * NN; p += 256) {
        int n = p / NN, m = p - n * NN;
        const float* vn = Vs + n * (RR + 1);
        const float* vm = Vs + m * (RR + 1);
        float acc = (n == m) ? dsh[n] : 0.0f;
#pragma unroll
        for (int r = 0; r < RR; ++r) acc = fmaf(vn[r], vm[r], acc);
        covp[p] = acc;
    }
}

extern "C" void kernel_launch(void* const* d_in, const int* in_sizes, int n_in,
                              void* d_out, int out_size, void* d_ws, size_t ws_size,
                              hipStream_t stream) {
    const float* inputs  = (const float*)d_in[0];
    const int*   indices = (const int*)d_in[1];
    const float* embW    = (const float*)d_in[2];
    const float* Wih0    = (const float*)d_in[3];
    const float* Whh0    = (const float*)d_in[4];
    const float* bih0    = (const float*)d_in[5];
    const float* bhh0    = (const float*)d_in[6];
    const float* Wih1    = (const float*)d_in[7];
    const float* Whh1    = (const float*)d_in[8];
    const float* bih1    = (const float*)d_in[9];
    const float* bhh1    = (const float*)d_in[10];
    const float* Wm      = (const float*)d_in[11];
    const float* bm      = (const float*)d_in[12];
    const float* Wv      = (const float*)d_in[13];
    const float* bv      = (const float*)d_in[14];
    const float* Wd      = (const float*)d_in[15];
    const float* bd      = (const float*)d_in[16];
    float* out = (float*)d_out;

    lstm_kernel<<<NN / 2, 512, 0, stream>>>(inputs, Wih0, Whh0, bih0, bhh0,
                                            Wih1, Whh1, bih1, bhh1, out);
    head_kernel<<<TT, 256, 0, stream>>>(embW, indices, Wm, bm, Wv, bv, Wd, bd, out);
}